// Round 14
// baseline (362.687 us; speedup 1.0000x reference)
//
#include <hip/hip_runtime.h>

// ---------------- problem constants ----------------
static constexpr int N_NODES = 100000;
static constexpr int N_EDGES = 3200000;
static constexpr int SHIFT  = 10;                         // 1024 nodes / bucket
static constexpr int NPB    = 1 << SHIFT;                 // 1024
static constexpr int NBK    = (N_NODES + NPB - 1) / NPB;  // 98 buckets
static constexpr int SLOTS  = NBK * NPB;                  // 100352
static constexpr int WGC    = 1000;                       // partition workgroups
static constexpr int CHUNK  = N_EDGES / WGC;              // 3200 edges / WG (exact)
static constexpr int PSPLIT = 8;                          // spans per bucket in reduce

// ---------------- bf16 helpers ----------------
__device__ __forceinline__ unsigned bf16rne(float f) {
    unsigned u = __float_as_uint(f);
    u += 0x7fffu + ((u >> 16) & 1u);
    return u >> 16;
}
__device__ __forceinline__ unsigned pack2(float lo, float hi) {
    return bf16rne(lo) | (bf16rne(hi) << 16);
}

// ---- K0: streaming compute, one thread per edge. boo read sequentially
//      (4 x float4, 64B/thread), vin gather (L2-resident), ONE uint2 8B store.
//      No subword traffic anywhere.
template<int TRANS>
__global__ void __launch_bounds__(256) k_msg(
    const int* __restrict__ pay,
    const float4* __restrict__ vin,
    const float4* __restrict__ boo,
    uint2* __restrict__ msgE)
{
    int e = blockIdx.x * 256 + threadIdx.x;
    if (e >= N_EDGES) return;
    float4 v  = vin[pay[e]];
    float4 q0 = boo[(size_t)e * 4 + 0];
    float4 q1 = boo[(size_t)e * 4 + 1];
    float4 q2 = boo[(size_t)e * 4 + 2];
    float4 q3 = boo[(size_t)e * 4 + 3];
    float m0, m1, m2, m3;
    if (TRANS) {  // A^T v
        m0 = q0.x * v.x + q1.x * v.y + q2.x * v.z + q3.x * v.w;
        m1 = q0.y * v.x + q1.y * v.y + q2.y * v.z + q3.y * v.w;
        m2 = q0.z * v.x + q1.z * v.y + q2.z * v.z + q3.z * v.w;
        m3 = q0.w * v.x + q1.w * v.y + q2.w * v.z + q3.w * v.w;
    } else {      // A v
        m0 = q0.x * v.x + q0.y * v.y + q0.z * v.z + q0.w * v.w;
        m1 = q1.x * v.x + q1.y * v.y + q1.z * v.z + q1.w * v.w;
        m2 = q2.x * v.x + q2.y * v.y + q2.z * v.z + q2.w * v.w;
        m3 = q3.x * v.x + q3.y * v.y + q3.z * v.z + q3.w * v.w;
    }
    msgE[e] = make_uint2(pack2(m0, m1), pack2(m2, m3));
}

// ---- K1: per-WG histograms for both keys; transposed count matrices [NBK][WGC]
__global__ void __launch_bounds__(256) k_count(
    const int* __restrict__ row, const int* __restrict__ col,
    unsigned* __restrict__ cmC, unsigned* __restrict__ cmR)
{
    __shared__ unsigned hC[NBK], hR[NBK];
    if (threadIdx.x < NBK) { hC[threadIdx.x] = 0u; hR[threadIdx.x] = 0u; }
    __syncthreads();
    int w = blockIdx.x, e0 = w * CHUNK;
    for (int e = e0 + threadIdx.x; e < e0 + CHUNK; e += 256) {
        atomicAdd(&hC[col[e] >> SHIFT], 1u);
        atomicAdd(&hR[row[e] >> SHIFT], 1u);
    }
    __syncthreads();
    if (threadIdx.x < NBK) {
        cmC[(size_t)threadIdx.x * WGC + w] = hC[threadIdx.x];
        cmR[(size_t)threadIdx.x * WGC + w] = hR[threadIdx.x];
    }
}

// ---- K2: exclusive prefix over WGs per bucket (one warp per bucket row)
__global__ void __launch_bounds__(256) k_prefix(
    unsigned* __restrict__ cmC, unsigned* __restrict__ cmR,
    unsigned* __restrict__ totC, unsigned* __restrict__ totR)
{
    int warp = (blockIdx.x * 256 + threadIdx.x) >> 6;
    int lane = threadIdx.x & 63;
    if (warp >= 2 * NBK) return;
    unsigned* cm  = (warp < NBK) ? cmC : cmR;
    unsigned* tot = (warp < NBK) ? totC : totR;
    int b = (warp < NBK) ? warp : warp - NBK;
    unsigned* rowp = cm + (size_t)b * WGC;
    unsigned carry = 0;
    for (int base = 0; base < WGC; base += 64) {
        int idx = base + lane;
        unsigned v = (idx < WGC) ? rowp[idx] : 0u;
        unsigned inc = v;
        for (int off = 1; off < 64; off <<= 1) {
            unsigned t = __shfl_up(inc, off, 64);
            if (lane >= off) inc += t;
        }
        if (idx < WGC) rowp[idx] = carry + inc - v;   // exclusive
        carry += __shfl(inc, 63, 64);
    }
    if (lane == 0) tot[b] = carry;
}

// ---- K3: tiny serial scans of 98 bucket totals -> bases
__global__ void __launch_bounds__(64) k_scan(
    const unsigned* __restrict__ totC, const unsigned* __restrict__ totR,
    unsigned* __restrict__ baseC, unsigned* __restrict__ baseR)
{
    if (threadIdx.x == 0) {
        unsigned s = 0;
        for (int b = 0; b < NBK; ++b) { baseC[b] = s; s += totC[b]; }
    } else if (threadIdx.x == 1) {
        unsigned s = 0;
        for (int b = 0; b < NBK; ++b) { baseR[b] = s; s += totR[b]; }
    }
}

// ---- K4: partition messages into bucket-sorted split streams. LDS-staged,
//      long runs (~33 recs = 261B msgS / 131B locS), all stores word-sized.
__global__ void __launch_bounds__(256) k_part(
    const int* __restrict__ key,       // destination index (col p1 / row p2)
    const uint2* __restrict__ msgE,    // messages in edge order
    const unsigned* __restrict__ cm,   // prefix'd count matrix [NBK][WGC]
    const unsigned* __restrict__ base, // bucket bases [NBK]
    uint2* __restrict__ msgS,          // sorted messages (8B)
    unsigned* __restrict__ locS)       // sorted local ids (4B words)
{
    __shared__ uint2 smsg[CHUNK];           // 25.6 KB
    __shared__ unsigned short sloc[CHUNK];  // 6.4 KB (LDS subword is fine)
    __shared__ unsigned hist[NBK];
    __shared__ unsigned runstart[NBK + 1];
    __shared__ unsigned gdst[NBK];
    int w = blockIdx.x, tid = threadIdx.x, e0 = w * CHUNK;

    if (tid < NBK) {
        hist[tid] = 0u;
        gdst[tid] = base[tid] + cm[(size_t)tid * WGC + w];
    }
    __syncthreads();
    for (int e = e0 + tid; e < e0 + CHUNK; e += 256)
        atomicAdd(&hist[key[e] >> SHIFT], 1u);
    __syncthreads();
    if (tid == 0) {                         // 98-entry serial scan (cheap)
        unsigned s = 0;
        for (int b = 0; b < NBK; ++b) { runstart[b] = s; s += hist[b]; }
        runstart[NBK] = s;
    }
    __syncthreads();
    if (tid < NBK) hist[tid] = runstart[tid];  // cursors
    __syncthreads();

    for (int e = e0 + tid; e < e0 + CHUNK; e += 256) {
        int k = key[e];
        int b = k >> SHIFT;
        unsigned pos = atomicAdd(&hist[b], 1u);
        smsg[pos] = msgE[e];
        sloc[pos] = (unsigned short)(k & (NPB - 1));
    }
    __syncthreads();

    // write-out: 7-step binary search; consecutive s within a run -> consecutive g
    for (int s = tid; s < CHUNK; s += 256) {
        int lo = 0, hi = NBK;
        while (hi - lo > 1) {
            int mid = (lo + hi) >> 1;
            if (runstart[mid] <= (unsigned)s) lo = mid; else hi = mid;
        }
        size_t g = (size_t)gdst[lo] + (unsigned)s - runstart[lo];
        msgS[g] = smsg[s];
        locS[g] = (unsigned)sloc[s];        // 4B store
    }
}

// ---- K5: PSPLIT contiguous spans per bucket: dense stream, 16KB LDS f32 acc,
//      partials to per-sub buffer (no pre-zero anywhere).
__global__ void __launch_bounds__(512) k_reduce(
    const uint2* __restrict__ msgS, const unsigned* __restrict__ locS,
    const unsigned* __restrict__ base, const unsigned* __restrict__ tot,
    float4* __restrict__ part)          // [PSPLIT][SLOTS]
{
    __shared__ float acc[4][NPB];       // 16 KB
    int b = blockIdx.x / PSPLIT, sub = blockIdx.x % PSPLIT;
    int tid = threadIdx.x;
    for (int i = tid; i < 4 * NPB; i += 512) ((float*)acc)[i] = 0.f;
    __syncthreads();
    unsigned start = base[b], n = tot[b];
    unsigned lo = start + (unsigned)(((unsigned long long)n * sub) / PSPLIT);
    unsigned hi = start + (unsigned)(((unsigned long long)n * (sub + 1)) / PSPLIT);
    for (unsigned i = lo + tid; i < hi; i += 512) {
        uint2 m = msgS[i];
        int loc = (int)locS[i];
        atomicAdd(&acc[0][loc], __uint_as_float(m.x << 16));
        atomicAdd(&acc[1][loc], __uint_as_float(m.x & 0xffff0000u));
        atomicAdd(&acc[2][loc], __uint_as_float(m.y << 16));
        atomicAdd(&acc[3][loc], __uint_as_float(m.y & 0xffff0000u));
    }
    __syncthreads();
    float4* dst = part + (size_t)sub * SLOTS + (size_t)b * NPB;
    for (int i = tid; i < NPB; i += 512)
        dst[i] = make_float4(acc[0][i], acc[1][i], acc[2][i], acc[3][i]);
}

// ---- K6: merge PSPLIT partial buffers -> final vector
__global__ void __launch_bounds__(256) k_merge(
    const float4* __restrict__ part, float4* __restrict__ vout)
{
    int s = blockIdx.x * 256 + threadIdx.x;
    if (s >= N_NODES) return;
    float4 r = part[s];
    for (int sub = 1; sub < PSPLIT; ++sub) {
        float4 t = part[(size_t)sub * SLOTS + s];
        r.x += t.x; r.y += t.y; r.z += t.z; r.w += t.w;
    }
    vout[s] = r;
}

// ================= fallback path (R3: sector-merged global atomics) =================

__global__ void __launch_bounds__(256) llt_pass1(
    const float* __restrict__ x, const int* __restrict__ row_idx,
    const int* __restrict__ col_idx, const float* __restrict__ boo,
    float* __restrict__ lt)
{
    int t = blockIdx.x * blockDim.x + threadIdx.x;
    if (t >= N_EDGES * 4) return;
    int e = t >> 2, i = t & 3;
    int r = row_idx[e], c = col_idx[e];
    const float* A = boo + (size_t)e * 16;
    const float* xv = x + (size_t)r * 4;
    float m = A[0*4+i]*xv[0] + A[1*4+i]*xv[1] + A[2*4+i]*xv[2] + A[3*4+i]*xv[3];
    atomicAdd(lt + (size_t)c * 4 + i, m);
}

__global__ void __launch_bounds__(256) llt_pass2(
    const float4* __restrict__ lt, const int* __restrict__ row_idx,
    const int* __restrict__ col_idx, const float4* __restrict__ boo,
    float* __restrict__ out)
{
    int t = blockIdx.x * blockDim.x + threadIdx.x;
    if (t >= N_EDGES * 4) return;
    int e = t >> 2, i = t & 3;
    int r = row_idx[e], c = col_idx[e];
    float4 arow = boo[(size_t)e * 4 + i];
    float4 lv = lt[c];
    float m = arow.x*lv.x + arow.y*lv.y + arow.z*lv.z + arow.w*lv.w;
    atomicAdd(out + (size_t)r * 4 + i, m);
}

// ================= host =================

extern "C" void kernel_launch(void* const* d_in, const int* in_sizes, int n_in,
                              void* d_out, int out_size, void* d_ws, size_t ws_size,
                              hipStream_t stream) {
    const float4* x = (const float4*)d_in[0];        // [100000,4] f32
    const int* edge_index = (const int*)d_in[1];     // [2, 3200000] int32
    const float4* boo = (const float4*)d_in[2];      // [3200000,4,4] f32
    const int* row = edge_index;                     // edge_index[0]
    const int* col = edge_index + N_EDGES;           // edge_index[1]
    float4* out = (float4*)d_out;

    auto align256 = [](size_t v) { return (v + 255) & ~(size_t)255; };
    const size_t sz_cm   = align256((size_t)NBK * WGC * 4);       // 392 KB each
    const size_t sz_vec  = align256((size_t)NBK * 4);
    const size_t sz_msgE = align256((size_t)N_EDGES * 8);         // 25.6 MB
    const size_t sz_msgS = align256((size_t)N_EDGES * 8);         // 25.6 MB
    const size_t sz_loc  = align256((size_t)N_EDGES * 4);         // 12.8 MB
    const size_t sz_lt   = align256((size_t)N_NODES * 16);        // 1.6 MB
    const size_t sz_part = align256((size_t)PSPLIT * SLOTS * 16); // 12.85 MB
    const size_t need = 2 * sz_cm + 4 * sz_vec + sz_msgE + sz_msgS + sz_loc
                      + sz_lt + sz_part;

    if (ws_size >= need) {
        char* p = (char*)d_ws;
        unsigned* cmC   = (unsigned*)p; p += sz_cm;
        unsigned* cmR   = (unsigned*)p; p += sz_cm;
        unsigned* totC  = (unsigned*)p; p += sz_vec;
        unsigned* totR  = (unsigned*)p; p += sz_vec;
        unsigned* baseC = (unsigned*)p; p += sz_vec;
        unsigned* baseR = (unsigned*)p; p += sz_vec;
        uint2*    msgE  = (uint2*)p;    p += sz_msgE;
        uint2*    msgS  = (uint2*)p;    p += sz_msgS;
        unsigned* locS  = (unsigned*)p; p += sz_loc;
        float4*   lt    = (float4*)p;   p += sz_lt;
        float4*   part  = (float4*)p;   p += sz_part;

        const int mgrid = (N_EDGES + 255) / 256;

        k_count<<<WGC, 256, 0, stream>>>(row, col, cmC, cmR);
        k_prefix<<<(2 * NBK * 64 + 255) / 256, 256, 0, stream>>>(cmC, cmR, totC, totR);
        k_scan<<<1, 64, 0, stream>>>(totC, totR, baseC, baseR);
        // pass 1: msg = A^T x[row], bucket by col -> lt
        k_msg<1><<<mgrid, 256, 0, stream>>>(row, x, boo, msgE);
        k_part<<<WGC, 256, 0, stream>>>(col, msgE, cmC, baseC, msgS, locS);
        k_reduce<<<NBK * PSPLIT, 512, 0, stream>>>(msgS, locS, baseC, totC, part);
        k_merge<<<(N_NODES + 255) / 256, 256, 0, stream>>>(part, lt);
        // pass 2: msg = A lt[col], bucket by row -> out
        k_msg<0><<<mgrid, 256, 0, stream>>>(col, (const float4*)lt, boo, msgE);
        k_part<<<WGC, 256, 0, stream>>>(row, msgE, cmR, baseR, msgS, locS);
        k_reduce<<<NBK * PSPLIT, 512, 0, stream>>>(msgS, locS, baseR, totR, part);
        k_merge<<<(N_NODES + 255) / 256, 256, 0, stream>>>(part, out);
    } else {
        // fallback: sector-merged atomics (R3, 328 us)
        float* ltf = (float*)d_ws;
        hipMemsetAsync(ltf, 0, (size_t)N_NODES * 4 * sizeof(float), stream);
        hipMemsetAsync(out, 0, (size_t)N_NODES * 4 * sizeof(float), stream);
        const int grid = (N_EDGES * 4 + 255) / 256;
        llt_pass1<<<grid, 256, 0, stream>>>((const float*)x, row, col, (const float*)boo, ltf);
        llt_pass2<<<grid, 256, 0, stream>>>((const float4*)ltf, row, col, boo, (float*)out);
    }
}